// Round 1
// baseline (130897.424 us; speedup 1.0000x reference)
//
#include <hip/hip_runtime.h>
#include <hip/hip_bf16.h>
#include <math.h>

// Problem constants (fixed by the reference)
#define BB 32
#define TENC 512
#define TMEL 400
#define HD 512
#define AD 512
#define PD 256
#define MD 128
#define FD 32
#define KC 31
#define G3 1536

__device__ __forceinline__ float fast_rcp(float x) {
#if __has_builtin(__builtin_amdgcn_rcpf)
  return __builtin_amdgcn_rcpf(x);
#else
  return 1.f / x;
#endif
}
__device__ __forceinline__ float fast_sigmoid(float x) {
  return fast_rcp(1.f + __expf(-x));
}
__device__ __forceinline__ float fast_tanh(float x) {
  // tanh(x) = 1 - 2/(exp(2x)+1); saturates correctly for +/-inf
  return 1.f - 2.f * fast_rcp(1.f + __expf(2.f * x));
}

// ---------------- init: zero state + mel_mask output ----------------
__global__ __launch_bounds__(256) void k_init(float* __restrict__ state,
                                              const int* __restrict__ mel_lens,
                                              float* __restrict__ mask_out) {
  int i = blockIdx.x * 256 + threadIdx.x;
  if (i < 155648) state[i] = 0.f;
  if (i < BB * TMEL) {
    int b = i / TMEL, t = i % TMEL;
    mask_out[i] = (t > mel_lens[b]) ? 1.f : 0.f;
  }
}

// ---------------- keys_p = enc_outputs @ k_w  [16384,1024]x[1024,512] ----------------
__global__ __launch_bounds__(256) void k_keys(const float* __restrict__ A,
                                              const float* __restrict__ W,
                                              float* __restrict__ C) {
  __shared__ float sA[16][65];
  __shared__ float sB[16][65];
  int tid = threadIdx.x;
  int row0 = blockIdx.x * 64, col0 = blockIdx.y * 64;
  int tx = tid & 15, ty = tid >> 4;
  float acc[4][4] = {};
  for (int k0 = 0; k0 < 1024; k0 += 16) {
    float4 a4 = *(const float4*)(A + (size_t)(row0 + (tid >> 2)) * 1024 + k0 + (tid & 3) * 4);
    int ka = (tid & 3) * 4, ma = tid >> 2;
    sA[ka + 0][ma] = a4.x; sA[ka + 1][ma] = a4.y; sA[ka + 2][ma] = a4.z; sA[ka + 3][ma] = a4.w;
    float4 b4 = *(const float4*)(W + (size_t)(k0 + (tid >> 4)) * 512 + col0 + (tid & 15) * 4);
    int kb = tid >> 4, nb = (tid & 15) * 4;
    sB[kb][nb + 0] = b4.x; sB[kb][nb + 1] = b4.y; sB[kb][nb + 2] = b4.z; sB[kb][nb + 3] = b4.w;
    __syncthreads();
#pragma unroll
    for (int k = 0; k < 16; k++) {
      float ar[4], br[4];
#pragma unroll
      for (int i = 0; i < 4; i++) { ar[i] = sA[k][ty * 4 + i]; br[i] = sB[k][tx * 4 + i]; }
#pragma unroll
      for (int i = 0; i < 4; i++)
#pragma unroll
        for (int j = 0; j < 4; j++) acc[i][j] = fmaf(ar[i], br[j], acc[i][j]);
    }
    __syncthreads();
  }
#pragma unroll
  for (int i = 0; i < 4; i++)
#pragma unroll
    for (int j = 0; j < 4; j++)
      C[(size_t)(row0 + ty * 4 + i) * 512 + col0 + tx * 4 + j] = acc[i][j];
}

// ---------------- GRU cell (generic): x = concat(xa[Da], xb[Db]) ----------------
// grid 64 = 16 u-tiles(32) x 4 b-groups(8); 512 threads = 2 K-halves x 256
__global__ __launch_bounds__(512) void k_gru(const float* __restrict__ xa, int Da,
                                             const float* __restrict__ xb, int Db,
                                             const float* __restrict__ wi,
                                             const float* __restrict__ wh,
                                             const float* __restrict__ bi,
                                             const float* __restrict__ bh,
                                             const float* __restrict__ hprev,
                                             float* __restrict__ hnext) {
  __shared__ float part[256][6];
  int tid = threadIdx.x;
  int half = tid >> 8;
  int t8 = tid & 255;
  int u = (blockIdx.x & 15) * 32 + (t8 & 31);
  int b = (blockIdx.x >> 4) * 8 + (t8 >> 5);
  int Dx = Da + Db;
  int s0 = half * (Dx >> 1), s1 = s0 + (Dx >> 1);
  float ir = 0.f, iz = 0.f, in_ = 0.f, hr = 0.f, hz = 0.f, hn = 0.f;
  int ea = (s1 < Da) ? s1 : Da;
#pragma unroll 4
  for (int k = s0; k < ea; k++) {
    float xv = xa[b * Da + k];
    const float* w = wi + (size_t)k * G3 + u;
    ir = fmaf(xv, w[0], ir); iz = fmaf(xv, w[512], iz); in_ = fmaf(xv, w[1024], in_);
  }
  int sbg = (s0 > Da) ? s0 : Da;
#pragma unroll 4
  for (int k = sbg; k < s1; k++) {
    float xv = xb[b * Db + (k - Da)];
    const float* w = wi + (size_t)k * G3 + u;
    ir = fmaf(xv, w[0], ir); iz = fmaf(xv, w[512], iz); in_ = fmaf(xv, w[1024], in_);
  }
#pragma unroll 4
  for (int k = half * 256; k < half * 256 + 256; k++) {
    float hv = hprev[b * HD + k];
    const float* w = wh + (size_t)k * G3 + u;
    hr = fmaf(hv, w[0], hr); hz = fmaf(hv, w[512], hz); hn = fmaf(hv, w[1024], hn);
  }
  if (half == 1) {
    float* p = part[t8];
    p[0] = ir; p[1] = iz; p[2] = in_; p[3] = hr; p[4] = hz; p[5] = hn;
  }
  __syncthreads();
  if (half == 0) {
    const float* p = part[t8];
    ir += p[0] + bi[u]; iz += p[1] + bi[u + 512]; in_ += p[2] + bi[u + 1024];
    hr += p[3] + bh[u]; hz += p[4] + bh[u + 512]; hn += p[5] + bh[u + 1024];
    float r = fast_sigmoid(ir + hr);
    float z = fast_sigmoid(iz + hz);
    float n = fast_tanh(in_ + r * hn);
    hnext[b * HD + u] = (1.f - z) * n + z * hprev[b * HD + u];
  }
}

// ---------------- q = h_attn @ q_w + loc_b (loc_b folded here) ----------------
__global__ __launch_bounds__(256) void k_q(const float* __restrict__ h,
                                           const float* __restrict__ qw,
                                           const float* __restrict__ locb,
                                           float* __restrict__ q) {
  int tid = threadIdx.x;
  int a = (blockIdx.x & 15) * 32 + (tid & 31);
  int b = (blockIdx.x >> 4) * 8 + (tid >> 5);
  float acc = locb[a];
  const float* hb = h + b * HD;
#pragma unroll 4
  for (int k = 0; k < HD; k++) acc = fmaf(hb[k], qw[(size_t)k * AD + a], acc);
  q[b * AD + a] = acc;
}

// ---------------- fused conv + loc-proj + tanh + score + mask ----------------
// grid 512 = 32 b x 16 t-tiles(32); 256 threads (4 waves x 8 t each)
__global__ __launch_bounds__(256) void k_score(const float* __restrict__ keys,
                                               const float* __restrict__ qv,
                                               const float* __restrict__ attw,
                                               const float* __restrict__ attcum,
                                               const float* __restrict__ convw,
                                               const float* __restrict__ locw,
                                               const float* __restrict__ scorew,
                                               const float* __restrict__ scoreb,
                                               const int* __restrict__ text_lens,
                                               float* __restrict__ sout) {
  __shared__ float wS[16][512];    // half of loc_w [F/2][A]
  __shared__ float awS[64], acS[64];
  __shared__ float locS[32][33];   // conv out tile [t][f]
  int b = blockIdx.x >> 4;
  int t0 = (blockIdx.x & 15) << 5;
  int tid = threadIdx.x;
  for (int j = tid; j < 62; j += 256) {
    int p = t0 - 15 + j;
    bool ok = ((unsigned)p < (unsigned)TENC);
    awS[j] = ok ? attw[b * TENC + p] : 0.f;
    acS[j] = ok ? attcum[b * TENC + p] : 0.f;
  }
  __syncthreads();
  for (int i = tid; i < 1024; i += 256) {
    int tt = i >> 5, f = i & 31;
    const float* w0 = convw + f * 62;
    float acc = 0.f;
#pragma unroll
    for (int k = 0; k < KC; k++)
      acc = fmaf(w0[k], awS[tt + k], fmaf(w0[31 + k], acS[tt + k], acc));
    locS[tt][f] = acc;
  }
  int lane = tid & 63, wv = tid >> 6;
  float qr[8];
#pragma unroll
  for (int i = 0; i < 8; i++) qr[i] = qv[b * AD + i * 64 + lane];
  float acc[8][8];
#pragma unroll
  for (int tt = 0; tt < 8; tt++) {
    int t = t0 + wv * 8 + tt;
    const float* kp = keys + ((size_t)(b * TENC + t) << 9);
#pragma unroll
    for (int i = 0; i < 8; i++) acc[tt][i] = qr[i] + kp[i * 64 + lane];
  }
  for (int ph = 0; ph < 2; ph++) {
    __syncthreads();
    for (int i = tid; i < 16 * 512; i += 256) wS[i >> 9][i & 511] = locw[ph * 8192 + i];
    __syncthreads();
#pragma unroll
    for (int f2 = 0; f2 < 16; f2++) {
      int f = ph * 16 + f2;
      float w[8];
#pragma unroll
      for (int i = 0; i < 8; i++) w[i] = wS[f2][i * 64 + lane];
#pragma unroll
      for (int tt = 0; tt < 8; tt++) {
        float lf = locS[wv * 8 + tt][f];
#pragma unroll
        for (int i = 0; i < 8; i++) acc[tt][i] = fmaf(lf, w[i], acc[tt][i]);
      }
    }
  }
  float swr[8];
#pragma unroll
  for (int i = 0; i < 8; i++) swr[i] = scorew[i * 64 + lane];
  float sb = scoreb[0];
  int tlen = text_lens[b];
#pragma unroll
  for (int tt = 0; tt < 8; tt++) {
    float p = 0.f;
#pragma unroll
    for (int i = 0; i < 8; i++) p += fast_tanh(acc[tt][i]) * swr[i];
#pragma unroll
    for (int off = 32; off > 0; off >>= 1) p += __shfl_xor(p, off, 64);
    int t = t0 + wv * 8 + tt;
    if (lane == 0)
      sout[b * TENC + t] = (t > tlen) ? -INFINITY : (p + sb);
  }
}

// ---------------- softmax + att_w/att_cum/attns writes + ctx ----------------
// grid 256 = 32 b x 8 a-chunks(64); 256 threads
__global__ __launch_bounds__(256) void k_smax_ctx(const float* __restrict__ s,
                                                  const float* __restrict__ keys,
                                                  float* __restrict__ attw,
                                                  float* __restrict__ attcum,
                                                  float* __restrict__ ctx,
                                                  float* __restrict__ attn_out,
                                                  int step) {
  __shared__ float aw[512];
  __shared__ float red[256];
  int b = blockIdx.x >> 3, ch = blockIdx.x & 7, tid = threadIdx.x;
  float v0 = s[b * TENC + tid], v1 = s[b * TENC + 256 + tid];
  red[tid] = fmaxf(v0, v1);
  __syncthreads();
#pragma unroll
  for (int o = 128; o > 0; o >>= 1) {
    if (tid < o) red[tid] = fmaxf(red[tid], red[tid + o]);
    __syncthreads();
  }
  float mx = red[0];
  __syncthreads();
  float e0 = __expf(v0 - mx), e1 = __expf(v1 - mx);
  red[tid] = e0 + e1;
  __syncthreads();
#pragma unroll
  for (int o = 128; o > 0; o >>= 1) {
    if (tid < o) red[tid] += red[tid + o];
    __syncthreads();
  }
  float inv = fast_rcp(red[0]);
  float a0 = e0 * inv, a1 = e1 * inv;
  aw[tid] = a0; aw[tid + 256] = a1;
  if (ch == 0) {
    attw[b * TENC + tid] = a0; attw[b * TENC + 256 + tid] = a1;
    size_t ao = (size_t)b * (TMEL * TENC) + (size_t)step * TENC;
    attn_out[ao + tid] = a0; attn_out[ao + 256 + tid] = a1;
    attcum[b * TENC + tid] += a0; attcum[b * TENC + 256 + tid] += a1;
  }
  __syncthreads();
  int a = ch * 64 + (tid & 63), qr = tid >> 6;
  const float* kp = keys + (size_t)b * (TENC * AD) + a;
  float p = 0.f;
  for (int t = qr * 128; t < qr * 128 + 128; t++) p = fmaf(aw[t], kp[(size_t)t << 9], p);
  red[tid] = p;
  __syncthreads();
  if (tid < 64)
    ctx[b * AD + ch * 64 + tid] = red[tid] + red[tid + 64] + red[tid + 128] + red[tid + 192];
}

// ---------------- mel/gate heads + prenet, one block per batch element ----------------
__global__ __launch_bounds__(256) void k_decpre(const float* __restrict__ hout,
                                                const float* __restrict__ ctx,
                                                const float* __restrict__ decw,
                                                const float* __restrict__ decb,
                                                const float* __restrict__ gatew,
                                                const float* __restrict__ gateb,
                                                const float* __restrict__ pw1,
                                                const float* __restrict__ pw2,
                                                const int* __restrict__ mel_lens,
                                                float* __restrict__ mel_out,
                                                float* __restrict__ gate_out,
                                                float* __restrict__ decin,
                                                int step) {
  __shared__ float xh[1024];
  __shared__ float mel_s[128];
  __shared__ float p1[256];
  int b = blockIdx.x, tid = threadIdx.x;
  for (int i = tid; i < 1024; i += 256)
    xh[i] = (i < 512) ? hout[b * HD + i] : ctx[b * AD + i - 512];
  __syncthreads();
  bool masked = step > mel_lens[b];
  if (tid < 128) {
    float acc = decb[tid];
#pragma unroll 4
    for (int k = 0; k < 1024; k++) acc = fmaf(xh[k], decw[k * MD + tid], acc);
    mel_s[tid] = acc;
    mel_out[(size_t)b * (TMEL * MD) + step * MD + tid] = masked ? 0.f : acc;
  } else if (tid < 192) {
    int l = tid - 128;
    float acc = 0.f;
    for (int k = l; k < 1024; k += 64) acc = fmaf(xh[k], gatew[k], acc);
#pragma unroll
    for (int off = 32; off > 0; off >>= 1) acc += __shfl_xor(acc, off, 64);
    if (l == 0) gate_out[b * TMEL + step] = masked ? 1000.f : (acc + gateb[0]);
  }
  __syncthreads();
  float a1 = 0.f;
#pragma unroll 4
  for (int m = 0; m < 128; m++) a1 = fmaf(mel_s[m], pw1[m * PD + tid], a1);
  p1[tid] = fmaxf(a1, 0.f);
  __syncthreads();
  float a2 = 0.f;
#pragma unroll 4
  for (int m = 0; m < 256; m++) a2 = fmaf(p1[m], pw2[m * PD + tid], a2);
  decin[b * PD + tid] = fmaxf(a2, 0.f);
}

extern "C" void kernel_launch(void* const* d_in, const int* in_sizes, int n_in,
                              void* d_out, int out_size, void* d_ws, size_t ws_size,
                              hipStream_t stream) {
  const float* enc      = (const float*)d_in[0];
  const int*   text_lens= (const int*)d_in[2];
  const int*   mel_lens = (const int*)d_in[3];
  const float* pre_w1   = (const float*)d_in[5];
  const float* pre_w2   = (const float*)d_in[6];
  const float* attn_wi  = (const float*)d_in[7];
  const float* attn_wh  = (const float*)d_in[8];
  const float* attn_bi  = (const float*)d_in[9];
  const float* attn_bh  = (const float*)d_in[10];
  const float* q_w      = (const float*)d_in[11];
  const float* k_w      = (const float*)d_in[12];
  const float* score_w  = (const float*)d_in[13];
  const float* score_b  = (const float*)d_in[14];
  const float* conv_w   = (const float*)d_in[15];
  const float* loc_w    = (const float*)d_in[16];
  const float* loc_b    = (const float*)d_in[17];
  const float* out_wi   = (const float*)d_in[18];
  const float* out_wh   = (const float*)d_in[19];
  const float* out_bi   = (const float*)d_in[20];
  const float* out_bh   = (const float*)d_in[21];
  const float* dec_w    = (const float*)d_in[22];
  const float* dec_b    = (const float*)d_in[23];
  const float* gate_w   = (const float*)d_in[24];
  const float* gate_b   = (const float*)d_in[25];

  float* ws = (float*)d_ws;
  float* keys   = ws;                    // 8388608
  float* hattn  = ws + 8388608;          // 2 x 16384
  float* hout   = hattn + 32768;         // 2 x 16384
  float* attw   = hout + 32768;          // 16384
  float* attcum = attw + 16384;          // 16384
  float* ctx    = attcum + 16384;        // 16384
  float* qbuf   = ctx + 16384;           // 16384
  float* sbuf   = qbuf + 16384;          // 16384
  float* decin  = sbuf + 16384;          // 8192

  float* out      = (float*)d_out;
  float* out_mel  = out;                       // 32*400*128
  float* out_gate = out + 1638400;             // 32*400
  float* out_attn = out_gate + 12800;          // 32*400*512
  float* out_mask = out_attn + 6553600;        // 32*400

  k_init<<<608, 256, 0, stream>>>(hattn, mel_lens, out_mask);
  k_keys<<<dim3(256, 8), 256, 0, stream>>>(enc, k_w, keys);

  for (int t = 0; t < TMEL; t++) {
    float* hA_prev = hattn + (t & 1) * 16384;
    float* hA_next = hattn + ((t + 1) & 1) * 16384;
    float* hO_prev = hout + (t & 1) * 16384;
    float* hO_next = hout + ((t + 1) & 1) * 16384;
    k_gru<<<64, 512, 0, stream>>>(decin, PD, ctx, AD, attn_wi, attn_wh, attn_bi, attn_bh,
                                  hA_prev, hA_next);
    k_q<<<64, 256, 0, stream>>>(hA_next, q_w, loc_b, qbuf);
    k_score<<<512, 256, 0, stream>>>(keys, qbuf, attw, attcum, conv_w, loc_w, score_w,
                                     score_b, text_lens, sbuf);
    k_smax_ctx<<<256, 256, 0, stream>>>(sbuf, keys, attw, attcum, ctx, out_attn, t);
    k_gru<<<64, 512, 0, stream>>>(hA_next, HD, ctx, AD, out_wi, out_wh, out_bi, out_bh,
                                  hO_prev, hO_next);
    k_decpre<<<32, 256, 0, stream>>>(hO_next, ctx, dec_w, dec_b, gate_w, gate_b,
                                     pre_w1, pre_w2, mel_lens, out_mel, out_gate, decin, t);
  }
}

// Round 2
// 105421.497 us; speedup vs baseline: 1.2417x; 1.2417x over previous
//
#include <hip/hip_runtime.h>
#include <hip/hip_cooperative_groups.h>
#include <math.h>

namespace cg = cooperative_groups;

#define NBLK 256
#define NTHR 512

__device__ __forceinline__ float fast_rcp(float x) {
#if __has_builtin(__builtin_amdgcn_rcpf)
  return __builtin_amdgcn_rcpf(x);
#else
  return 1.f / x;
#endif
}
__device__ __forceinline__ float fast_sigmoid(float x) {
  return fast_rcp(1.f + __expf(-x));
}
__device__ __forceinline__ float fast_tanh(float x) {
  return 1.f - 2.f * fast_rcp(1.f + __expf(2.f * x));
}

struct Params {
  const float *enc, *pre_w1, *pre_w2, *attn_wi, *attn_wh, *attn_bi, *attn_bh;
  const float *q_w, *k_w, *score_w, *score_b, *conv_w, *loc_w, *loc_b;
  const float *out_wi, *out_wh, *out_bi, *out_bh, *dec_w, *dec_b, *gate_w, *gate_b;
  const int *text_lens, *mel_lens;
  float *keys, *hA, *hO, *attw, *attcum, *ctx, *decin, *qbuf, *ebuf, *zpart, *state;
  float *out_mel, *out_gate, *out_attn, *out_mask;
};

union SMem {
  struct { float sA[16][132]; float sB[16][68]; } ge;                       // keys GEMM
  struct { float xs[2][1024]; float hs[2][512]; float part[16][32][2][4]; } gr; // GRU
  struct { float h[512]; float part[8][64]; } qs;                           // q proj
  struct { float wS[16][512]; float locS[64][36]; float awS[96]; float acS[96]; float sred[8]; } sc; // score
  struct { float e[512]; float part[8][64]; } cx;                           // ctx
  struct { float xh[1024]; float mel[128]; float p1[256]; float red[512]; } de; // dec/prenet
};

// ---------------- generic GRU stage ----------------
// blocks: 16 u-tiles(32u) x 16 b-groups(2b); threads: 32u x 16 k-slices
__device__ __forceinline__ void gru_stage(SMem& sm,
    const float* __restrict__ xa, int Da, const float* __restrict__ xb, int Db,
    const float* __restrict__ wi, const float* __restrict__ wh,
    const float* __restrict__ bi, const float* __restrict__ bh,
    const float* __restrict__ hprev, float* __restrict__ hnext,
    int blk, int tid) {
  const int utile = blk & 15, bg = blk >> 4, b0 = bg * 2;
  const int Dx = Da + Db;
  for (int i = tid; i < 2 * Dx; i += NTHR) {
    int bb = (i >= Dx) ? 1 : 0;
    int k = i - bb * Dx;
    float v = (k < Da) ? xa[(b0 + bb) * Da + k] : xb[(b0 + bb) * Db + (k - Da)];
    sm.gr.xs[bb][k] = v;
  }
  for (int i = tid; i < 1024; i += NTHR)
    sm.gr.hs[i >> 9][i & 511] = hprev[(b0 + (i >> 9)) * 512 + (i & 511)];
  __syncthreads();
  const int u5 = tid & 31, ksl = tid >> 5;
  const int u = utile * 32 + u5;
  const int ci = Dx >> 4;
  float ar0 = 0.f, az0 = 0.f, ai0 = 0.f, ah0 = 0.f;
  float ar1 = 0.f, az1 = 0.f, ai1 = 0.f, ah1 = 0.f;
  {
    const float* wp = wi + (size_t)(ksl * ci) * 1536 + u;
#pragma unroll 4
    for (int k = ksl * ci; k < ksl * ci + ci; k++) {
      float wr = wp[0], wz = wp[512], wn = wp[1024];
      wp += 1536;
      float x0 = sm.gr.xs[0][k], x1 = sm.gr.xs[1][k];
      ar0 = fmaf(x0, wr, ar0); az0 = fmaf(x0, wz, az0); ai0 = fmaf(x0, wn, ai0);
      ar1 = fmaf(x1, wr, ar1); az1 = fmaf(x1, wz, az1); ai1 = fmaf(x1, wn, ai1);
    }
  }
  {
    const float* hp = wh + (size_t)(ksl * 32) * 1536 + u;
#pragma unroll 4
    for (int k = ksl * 32; k < ksl * 32 + 32; k++) {
      float wr = hp[0], wz = hp[512], wn = hp[1024];
      hp += 1536;
      float h0 = sm.gr.hs[0][k], h1 = sm.gr.hs[1][k];
      ar0 = fmaf(h0, wr, ar0); az0 = fmaf(h0, wz, az0); ah0 = fmaf(h0, wn, ah0);
      ar1 = fmaf(h1, wr, ar1); az1 = fmaf(h1, wz, az1); ah1 = fmaf(h1, wn, ah1);
    }
  }
  float* pp = &sm.gr.part[ksl][u5][0][0];
  pp[0] = ar0; pp[1] = az0; pp[2] = ai0; pp[3] = ah0;
  pp[4] = ar1; pp[5] = az1; pp[6] = ai1; pp[7] = ah1;
  __syncthreads();
  float s = 0.f;
  if (tid < 256) {
    int uu = tid & 31, bb = (tid >> 5) & 1, vv = tid >> 6;
#pragma unroll
    for (int j = 0; j < 16; j++) s += sm.gr.part[j][uu][bb][vv];
  }
  __syncthreads();
  if (tid < 256) {
    int uu = tid & 31, bb = (tid >> 5) & 1, vv = tid >> 6;
    sm.gr.part[0][uu][bb][vv] = s;
  }
  __syncthreads();
  if (tid < 64) {
    int uu = tid & 31, bb = tid >> 5;
    int ug = utile * 32 + uu;
    const float* pv = &sm.gr.part[0][uu][bb][0];
    float r = fast_sigmoid(pv[0] + bi[ug] + bh[ug]);
    float z = fast_sigmoid(pv[1] + bi[512 + ug] + bh[512 + ug]);
    float n = fast_tanh(pv[2] + bi[1024 + ug] + r * (pv[3] + bh[1024 + ug]));
    hnext[(b0 + bb) * 512 + ug] = (1.f - z) * n + z * sm.gr.hs[bb][ug];
  }
}

__global__ __launch_bounds__(NTHR) void mega(Params p) {
  cg::grid_group grid = cg::this_grid();
  __shared__ SMem sm;
  const int blk = blockIdx.x, tid = threadIdx.x;

  // ---- init: zero recurrent state, write mel_mask ----
  for (int i = blk * NTHR + tid; i < 122880; i += NBLK * NTHR) p.state[i] = 0.f;
  for (int i = blk * NTHR + tid; i < 12800; i += NBLK * NTHR) {
    int b = i / 400, t = i - b * 400;
    p.out_mask[i] = (t > p.mel_lens[b]) ? 1.f : 0.f;
  }
  // ---- keys = enc @ k_w : 1024 tiles of 128x64, 4 per block ----
  for (int rep = 0; rep < 4; rep++) {
    int tile = blk + rep * NBLK;
    int tm = tile >> 3, tn = tile & 7;
    int row0 = tm << 7, col0 = tn << 6;
    float acc[4][4] = {};
    int r = tid >> 2, kq = tid & 3;
    int tx = tid & 15, ty = tid >> 4;
    for (int k0 = 0; k0 < 1024; k0 += 16) {
      __syncthreads();
      float4 a4 = *(const float4*)(p.enc + (size_t)(row0 + r) * 1024 + k0 + kq * 4);
      sm.ge.sA[kq * 4 + 0][r] = a4.x; sm.ge.sA[kq * 4 + 1][r] = a4.y;
      sm.ge.sA[kq * 4 + 2][r] = a4.z; sm.ge.sA[kq * 4 + 3][r] = a4.w;
      if (tid < 256) {
        int kb = tid >> 4, nb = (tid & 15) * 4;
        float4 b4 = *(const float4*)(p.k_w + (size_t)(k0 + kb) * 512 + col0 + nb);
        sm.ge.sB[kb][nb + 0] = b4.x; sm.ge.sB[kb][nb + 1] = b4.y;
        sm.ge.sB[kb][nb + 2] = b4.z; sm.ge.sB[kb][nb + 3] = b4.w;
      }
      __syncthreads();
#pragma unroll
      for (int k = 0; k < 16; k++) {
        float ar[4], br[4];
#pragma unroll
        for (int i = 0; i < 4; i++) { ar[i] = sm.ge.sA[k][ty * 4 + i]; br[i] = sm.ge.sB[k][tx * 4 + i]; }
#pragma unroll
        for (int i = 0; i < 4; i++)
#pragma unroll
          for (int j = 0; j < 4; j++) acc[i][j] = fmaf(ar[i], br[j], acc[i][j]);
      }
    }
#pragma unroll
    for (int i = 0; i < 4; i++)
#pragma unroll
      for (int j = 0; j < 4; j++)
        p.keys[(size_t)(row0 + ty * 4 + i) * 512 + col0 + tx * 4 + j] = acc[i][j];
  }
  grid.sync();

#pragma clang loop unroll(disable)
  for (int step = 0; step < 400; step++) {
    const int par = step & 1;
    float* hA_prev = p.hA + par * 16384;
    float* hA_next = p.hA + (par ^ 1) * 16384;
    float* hO_prev = p.hO + par * 16384;
    float* hO_next = p.hO + (par ^ 1) * 16384;

    // ---- S1: GRU1 ----
    gru_stage(sm, p.decin, 256, p.ctx, 512, p.attn_wi, p.attn_wh, p.attn_bi, p.attn_bh,
              hA_prev, hA_next, blk, tid);
    grid.sync();

    // ---- S2: q = hA' @ q_w + loc_b ----
    {
      int b = blk >> 3, ch = blk & 7;
      for (int i = tid; i < 512; i += NTHR) sm.qs.h[i] = hA_next[b * 512 + i];
      __syncthreads();
      int a6 = tid & 63, ksl = tid >> 6;
      const float* qw = p.q_w + ch * 64 + a6;
      float acc = 0.f;
#pragma unroll 8
      for (int k = ksl * 64; k < ksl * 64 + 64; k++)
        acc = fmaf(sm.qs.h[k], qw[(size_t)k * 512], acc);
      sm.qs.part[ksl][a6] = acc;
      __syncthreads();
      if (tid < 64) {
        float s = p.loc_b[ch * 64 + tid];
#pragma unroll
        for (int j = 0; j < 8; j++) s += sm.qs.part[j][tid];
        p.qbuf[b * 512 + ch * 64 + tid] = s;
      }
    }
    grid.sync();

    // ---- S3: conv + loc-proj + tanh + score -> e, Zpart ----
    {
      int b = blk >> 3, t8 = blk & 7, t0 = t8 << 6;
      int tlen = p.text_lens[b];
      for (int j = tid; j < 96; j += NTHR) {
        int pp = t0 - 15 + j;
        bool ok = (unsigned)pp < 512u;
        sm.sc.awS[j] = ok ? p.attw[b * 512 + pp] : 0.f;
        sm.sc.acS[j] = ok ? p.attcum[b * 512 + pp] : 0.f;
      }
      __syncthreads();
      for (int i = tid; i < 2048; i += NTHR) {
        int tt = i >> 5, f = i & 31;
        const float* w0 = p.conv_w + f * 62;
        float a = 0.f;
#pragma unroll
        for (int k = 0; k < 31; k++)
          a = fmaf(w0[k], sm.sc.awS[tt + k], fmaf(w0[31 + k], sm.sc.acS[tt + k], a));
        sm.sc.locS[tt][f] = a;
      }
      int lane = tid & 63, wv = tid >> 6;
      float qr[8], acc[8][8];
#pragma unroll
      for (int i = 0; i < 8; i++) qr[i] = p.qbuf[b * 512 + i * 64 + lane];
#pragma unroll
      for (int tt = 0; tt < 8; tt++) {
        int t = t0 + wv * 8 + tt;
        const float* kp = p.keys + ((size_t)(b * 512 + t) << 9);
#pragma unroll
        for (int i = 0; i < 8; i++) acc[tt][i] = qr[i] + kp[i * 64 + lane];
      }
      for (int ph = 0; ph < 2; ph++) {
        __syncthreads();
        for (int j = tid; j < 8192; j += NTHR) sm.sc.wS[j >> 9][j & 511] = p.loc_w[ph * 8192 + j];
        __syncthreads();
#pragma unroll
        for (int f2 = 0; f2 < 16; f2++) {
          int f = ph * 16 + f2;
          float w[8];
#pragma unroll
          for (int i = 0; i < 8; i++) w[i] = sm.sc.wS[f2][i * 64 + lane];
#pragma unroll
          for (int tt = 0; tt < 8; tt++) {
            float lf = sm.sc.locS[wv * 8 + tt][f];
#pragma unroll
            for (int i = 0; i < 8; i++) acc[tt][i] = fmaf(lf, w[i], acc[tt][i]);
          }
        }
      }
      float swr[8];
#pragma unroll
      for (int i = 0; i < 8; i++) swr[i] = p.score_w[i * 64 + lane];
      float sb = p.score_b[0];
      float esum = 0.f;
#pragma unroll
      for (int tt = 0; tt < 8; tt++) {
        float pv = 0.f;
#pragma unroll
        for (int i = 0; i < 8; i++) pv += fast_tanh(acc[tt][i]) * swr[i];
#pragma unroll
        for (int off = 32; off > 0; off >>= 1) pv += __shfl_xor(pv, off, 64);
        int t = t0 + wv * 8 + tt;
        float e = (t > tlen) ? 0.f : __expf(pv + sb);
        if (lane == 0) p.ebuf[b * 512 + t] = e;
        esum += e;
      }
      if (lane == 0) sm.sc.sred[wv] = esum;
      __syncthreads();
      if (tid == 0) {
        float z = 0.f;
#pragma unroll
        for (int w2 = 0; w2 < 8; w2++) z += sm.sc.sred[w2];
        p.zpart[b * 8 + t8] = z;
      }
    }
    grid.sync();

    // ---- S4: normalize, ctx = att_w @ keys, write att outputs ----
    {
      int b = blk >> 3, ch = blk & 7;
      float Z = 0.f;
#pragma unroll
      for (int j = 0; j < 8; j++) Z += p.zpart[b * 8 + j];
      float inv = fast_rcp(Z);
      sm.cx.e[tid & 511] = p.ebuf[b * 512 + (tid & 511)] * inv;
      __syncthreads();
      int a6 = tid & 63, tsl = tid >> 6;
      const float* kp = p.keys + (size_t)(b * 512) * 512 + ch * 64 + a6;
      float acc = 0.f;
#pragma unroll 4
      for (int t = tsl * 64; t < tsl * 64 + 64; t++)
        acc = fmaf(sm.cx.e[t], kp[(size_t)t << 9], acc);
      sm.cx.part[tsl][a6] = acc;
      __syncthreads();
      if (tid < 64) {
        float s = 0.f;
#pragma unroll
        for (int j = 0; j < 8; j++) s += sm.cx.part[j][tid];
        p.ctx[b * 512 + ch * 64 + tid] = s;
        int idx = ch * 64 + tid;
        float v = sm.cx.e[idx];
        p.attw[b * 512 + idx] = v;
        p.attcum[b * 512 + idx] += v;
        p.out_attn[(size_t)b * 204800 + (size_t)step * 512 + idx] = v;
      }
    }
    grid.sync();

    // ---- S5: GRU2 ----
    gru_stage(sm, hA_next, 512, p.ctx, 512, p.out_wi, p.out_wh, p.out_bi, p.out_bh,
              hO_prev, hO_next, blk, tid);
    grid.sync();

    // ---- S6: mel/gate heads + prenet ----
    if (blk < 32) {
      int b = blk;
      for (int i = tid; i < 1024; i += NTHR)
        sm.de.xh[i] = (i < 512) ? hO_next[b * 512 + i] : p.ctx[b * 512 + (i - 512)];
      __syncthreads();
      bool masked = step > p.mel_lens[b];
      int m = tid & 127, ksl = tid >> 7;
      {
        const float* dw = p.dec_w + (size_t)(ksl * 256) * 128 + m;
        float acc = 0.f;
#pragma unroll 4
        for (int k = 0; k < 256; k++) { acc = fmaf(sm.de.xh[ksl * 256 + k], dw[0], acc); dw += 128; }
        sm.de.red[tid] = acc;
      }
      __syncthreads();
      if (tid < 128) {
        float mv = sm.de.red[tid] + sm.de.red[tid + 128] + sm.de.red[tid + 256] + sm.de.red[tid + 384] + p.dec_b[tid];
        sm.de.mel[tid] = mv;
        p.out_mel[(size_t)b * 51200 + (size_t)step * 128 + tid] = masked ? 0.f : mv;
      }
      __syncthreads();
      sm.de.red[tid] = fmaf(sm.de.xh[tid], p.gate_w[tid], sm.de.xh[tid + 512] * p.gate_w[tid + 512]);
      __syncthreads();
      for (int o = 256; o > 0; o >>= 1) {
        if (tid < o) sm.de.red[tid] += sm.de.red[tid + o];
        __syncthreads();
      }
      if (tid == 0)
        p.out_gate[b * 400 + step] = masked ? 1000.f : (sm.de.red[0] + p.gate_b[0]);
      __syncthreads();
      int pcol = tid & 255, k2 = tid >> 8;
      {
        float acc = 0.f;
        const float* w1 = p.pre_w1 + (size_t)(k2 * 64) * 256 + pcol;
#pragma unroll 4
        for (int k = 0; k < 64; k++) { acc = fmaf(sm.de.mel[k2 * 64 + k], w1[0], acc); w1 += 256; }
        sm.de.red[tid] = acc;
      }
      __syncthreads();
      if (tid < 256) sm.de.p1[tid] = fmaxf(sm.de.red[tid] + sm.de.red[tid + 256], 0.f);
      __syncthreads();
      {
        float acc = 0.f;
        const float* w2 = p.pre_w2 + (size_t)(k2 * 128) * 256 + pcol;
#pragma unroll 4
        for (int k = 0; k < 128; k++) { acc = fmaf(sm.de.p1[k2 * 128 + k], w2[0], acc); w2 += 256; }
        sm.de.red[tid] = acc;
      }
      __syncthreads();
      if (tid < 256)
        p.decin[b * 256 + tid] = fmaxf(sm.de.red[tid] + sm.de.red[tid + 256], 0.f);
    }
    grid.sync();
  }
}

extern "C" void kernel_launch(void* const* d_in, const int* in_sizes, int n_in,
                              void* d_out, int out_size, void* d_ws, size_t ws_size,
                              hipStream_t stream) {
  Params p;
  p.enc       = (const float*)d_in[0];
  p.text_lens = (const int*)d_in[2];
  p.mel_lens  = (const int*)d_in[3];
  p.pre_w1    = (const float*)d_in[5];
  p.pre_w2    = (const float*)d_in[6];
  p.attn_wi   = (const float*)d_in[7];
  p.attn_wh   = (const float*)d_in[8];
  p.attn_bi   = (const float*)d_in[9];
  p.attn_bh   = (const float*)d_in[10];
  p.q_w       = (const float*)d_in[11];
  p.k_w       = (const float*)d_in[12];
  p.score_w   = (const float*)d_in[13];
  p.score_b   = (const float*)d_in[14];
  p.conv_w    = (const float*)d_in[15];
  p.loc_w     = (const float*)d_in[16];
  p.loc_b     = (const float*)d_in[17];
  p.out_wi    = (const float*)d_in[18];
  p.out_wh    = (const float*)d_in[19];
  p.out_bi    = (const float*)d_in[20];
  p.out_bh    = (const float*)d_in[21];
  p.dec_w     = (const float*)d_in[22];
  p.dec_b     = (const float*)d_in[23];
  p.gate_w    = (const float*)d_in[24];
  p.gate_b    = (const float*)d_in[25];

  float* ws = (float*)d_ws;
  p.keys   = ws;
  p.hA     = ws + 8388608;
  p.hO     = ws + 8421376;
  p.attw   = ws + 8454144;
  p.attcum = ws + 8470528;
  p.ctx    = ws + 8486912;
  p.decin  = ws + 8503296;
  p.qbuf   = ws + 8511488;
  p.ebuf   = ws + 8527872;
  p.zpart  = ws + 8544256;
  p.state  = p.hA;  // contiguous zero region: hA,hO,attw,attcum,ctx,decin (122880 floats)

  float* out = (float*)d_out;
  p.out_mel  = out;
  p.out_gate = out + 1638400;
  p.out_attn = out + 1651200;
  p.out_mask = out + 8204800;

  void* args[] = { (void*)&p };
  hipLaunchCooperativeKernel((const void*)mega, dim3(NBLK), dim3(NTHR), args, 0, stream);
}